// Round 16
// baseline (393.704 us; speedup 1.0000x reference)
//
#include <hip/hip_runtime.h>

#define N_NODES 100000
#define N_EDGES 1600000
#define DIN 128
#define DOUT 128
#define N_SUP 2
#define E_TOT (N_SUP * N_EDGES)          // 3,200,000

#define BIN_ROWS 128
#define BSHIFT 7
#define NBINS ((N_NODES + BIN_ROWS - 1) / BIN_ROWS)    // 782
#define CAP 4608     // bin capacity: mean 4096, sigma 64 -> +8 sigma
#define EPT_BS (CAP / 256)                              // 18

#define SC_EPT 16
#define SC_BLOCK 256
#define SC_CHUNK (SC_EPT * SC_BLOCK)                    // 4096
#define NBLK_SC ((E_TOT + SC_CHUNK - 1) / SC_CHUNK)     // 782

#define GEMM_ROWS 128
#define NBLK_GEMM ((N_NODES + GEMM_ROWS - 1) / GEMM_ROWS)   // 782
#define LDK 136      // padded LDS k-stride in bf16 units (odd multiple of 8)
#define GEMM_SMEM (2 * GEMM_ROWS * LDK * 2)             // 69,632 (R13-verified)
#define SCAT_SMEM (2 * NBINS * 4)                       //  6,256

typedef float        f32x2 __attribute__((ext_vector_type(2)));
typedef float        f32x4 __attribute__((ext_vector_type(4)));
typedef unsigned int u32;
typedef u32          u32x2 __attribute__((ext_vector_type(2)));
typedef u32          u32x4 __attribute__((ext_vector_type(4)));
typedef short        bf16x8 __attribute__((ext_vector_type(8)));

// round-to-nearest-even fp32 -> bf16 pair packed in one u32 (lo = even idx)
static __device__ __forceinline__ u32 pack_bf16x2(float lo, float hi) {
    u32 ul = __float_as_uint(lo);
    u32 uh = __float_as_uint(hi);
    ul = (ul + 0x7FFFu + ((ul >> 16) & 1u)) >> 16;
    uh = ((uh + 0x7FFFu + ((uh >> 16) & 1u)) >> 16) << 16;
    return ul | uh;
}

// ---------------------------------------------------------------------------
// GEMM body, BOTH supports per block: stage x ONCE (halves x HBM reads,
// 102 -> 51 MB), then per support stage W[s] + MFMA + epilogue. x-stage
// (stage[0]) stays intact across the W re-stage; the epilogue aliases the
// whole smem only after both MFMA phases. acc0+acc1 = 128 VGPR (2 blk/CU).
// MFMA math and per-support content identical to the R13-verified body.
// ---------------------------------------------------------------------------
static __device__ __forceinline__ void gemm_body(char* smem, int bidx,
                                                 const float* __restrict__ x,
                                                 const u32* __restrict__ wTb,
                                                 u32* __restrict__ pre) {
    typedef unsigned short (*stage_p)[GEMM_ROWS][LDK];
    stage_p stage = (stage_p)smem;
    float (*epi)[129] = (float (*)[129])smem;

    const int row0 = bidx * GEMM_ROWS;
    const int t = threadIdx.x;
    const int lane = t & 63;
    const int wv = t >> 6;
    const int r = t >> 1;
    const int half = t & 1;               // k 0..63 / 64..127
    const int gr = row0 + r;

    // stage x tile (rows row0..row0+127): fp32 -> packed bf16 LDS rows
    {
        u32* dst = (u32*)&stage[0][r][half * 64];
        u32 o[32];
        if (gr < N_NODES) {
            const float* p = x + (size_t)gr * DIN + half * 64;
            #pragma unroll
            for (int j = 0; j < 16; j++) {
                const f32x4 a = *(const f32x4*)(p + j * 4);
                o[2 * j]     = pack_bf16x2(a.x, a.y);
                o[2 * j + 1] = pack_bf16x2(a.z, a.w);
            }
        } else {
            #pragma unroll
            for (int j = 0; j < 32; j++) o[j] = 0;
        }
        #pragma unroll
        for (int j = 0; j < 8; j++)
            *(u32x4*)(dst + j * 4) = *(u32x4*)&o[j * 4];
        // stage wT[0]
        const u32* wp = wTb + (size_t)r * 64 + half * 32;
        u32* wdst = (u32*)&stage[1][r][half * 64];
        #pragma unroll
        for (int j = 0; j < 8; j++)
            *(u32x4*)(wdst + j * 4) = *(const u32x4*)(wp + j * 4);
    }
    __syncthreads();

    const int q = lane >> 4;       // quad: k sub-block
    const int ml = lane & 15;      // row within m-tile / col within n-tile
    const int m0 = wv * 32;

    f32x4 acc0[2][8], acc1[2][8];
    #pragma unroll
    for (int mt = 0; mt < 2; mt++)
        #pragma unroll
        for (int nt = 0; nt < 8; nt++) {
            acc0[mt][nt] = (f32x4){0.f, 0.f, 0.f, 0.f};
            acc1[mt][nt] = (f32x4){0.f, 0.f, 0.f, 0.f};
        }

    // MFMA phase, support 0
    #pragma unroll
    for (int kt = 0; kt < 4; kt++) {
        const int k0 = kt * 32 + q * 8;
        const bf16x8 a0 = *(const bf16x8*)&stage[0][m0 + ml][k0];
        const bf16x8 a1 = *(const bf16x8*)&stage[0][m0 + 16 + ml][k0];
        #pragma unroll
        for (int nt = 0; nt < 8; nt++) {
            const bf16x8 b = *(const bf16x8*)&stage[1][nt * 16 + ml][k0];
            acc0[0][nt] = __builtin_amdgcn_mfma_f32_16x16x32_bf16(a0, b, acc0[0][nt], 0, 0, 0);
            acc0[1][nt] = __builtin_amdgcn_mfma_f32_16x16x32_bf16(a1, b, acc0[1][nt], 0, 0, 0);
        }
    }
    __syncthreads();   // stage[1] reads done; restage W

    // stage wT[1] (x-stage untouched)
    {
        const u32* wp = wTb + ((size_t)128 + r) * 64 + half * 32;
        u32* wdst = (u32*)&stage[1][r][half * 64];
        #pragma unroll
        for (int j = 0; j < 8; j++)
            *(u32x4*)(wdst + j * 4) = *(const u32x4*)(wp + j * 4);
    }
    __syncthreads();

    // MFMA phase, support 1
    #pragma unroll
    for (int kt = 0; kt < 4; kt++) {
        const int k0 = kt * 32 + q * 8;
        const bf16x8 a0 = *(const bf16x8*)&stage[0][m0 + ml][k0];
        const bf16x8 a1 = *(const bf16x8*)&stage[0][m0 + 16 + ml][k0];
        #pragma unroll
        for (int nt = 0; nt < 8; nt++) {
            const bf16x8 b = *(const bf16x8*)&stage[1][nt * 16 + ml][k0];
            acc1[0][nt] = __builtin_amdgcn_mfma_f32_16x16x32_bf16(a0, b, acc1[0][nt], 0, 0, 0);
            acc1[1][nt] = __builtin_amdgcn_mfma_f32_16x16x32_bf16(a1, b, acc1[1][nt], 0, 0, 0);
        }
    }
    __syncthreads();   // all stage reads done; epi aliases smem

    // epilogue + store, per support
    #pragma unroll
    for (int s = 0; s < 2; s++) {
        #pragma unroll
        for (int mt = 0; mt < 2; mt++)
            #pragma unroll
            for (int nt = 0; nt < 8; nt++)
                #pragma unroll
                for (int rr = 0; rr < 4; rr++)
                    epi[m0 + mt * 16 + q * 4 + rr][nt * 16 + ml] =
                        (s == 0) ? acc0[mt][nt][rr] : acc1[mt][nt][rr];
        __syncthreads();
        if (gr < N_NODES) {
            u32 ov[32];
            #pragma unroll
            for (int j = 0; j < 32; j++)
                ov[j] = pack_bf16x2(epi[r][half * 64 + 2 * j],
                                    epi[r][half * 64 + 2 * j + 1]);
            u32* op = pre + ((size_t)s * N_NODES + gr) * 64 + half * 32;
            #pragma unroll
            for (int j = 0; j < 8; j++)
                __builtin_nontemporal_store(*(u32x4*)&ov[j * 4], (u32x4*)(op + j * 4));
        }
        __syncthreads();   // epi reads done before next support's writes
    }
}

// ---------------------------------------------------------------------------
// Binscatter body: BYTE-IDENTICAL to R15 (counts-cursor; block-local
// contiguous runs -> coalesced writes; R8 lesson).
// ---------------------------------------------------------------------------
static __device__ __forceinline__ void scatter_body(char* smem, int bidx,
                                                    const int* __restrict__ rows,
                                                    const int* __restrict__ cols,
                                                    const float* __restrict__ vals,
                                                    int* __restrict__ bin_cursor,
                                                    u32x2* __restrict__ edata) {
    int* lcnt = (int*)smem;
    int* lbase = lcnt + NBINS;
    const int t = threadIdx.x;
    for (int i = t; i < NBINS; i += 256) lcnt[i] = 0;
    __syncthreads();

    const int base = bidx * SC_CHUNK;
    int bin[SC_EPT], lpos[SC_EPT];
    u32x2 pay[SC_EPT];
    #pragma unroll
    for (int j = 0; j < SC_EPT; j++) {
        const int i = base + j * 256 + t;
        if (i < E_TOT) {
            const int r = __builtin_nontemporal_load(rows + i);
            const int c = __builtin_nontemporal_load(cols + i);
            const float v = __builtin_nontemporal_load(vals + i);
            const int b = r >> BSHIFT;
            bin[j] = b;
            lpos[j] = atomicAdd(&lcnt[b], 1);
            pay[j].x = (u32)(c + ((i >= N_EDGES) ? N_NODES : 0)) |
                       ((u32)(r & (BIN_ROWS - 1)) << 18);
            pay[j].y = __float_as_uint(v);
        } else {
            bin[j] = -1;
        }
    }
    __syncthreads();
    for (int b = t; b < NBINS; b += 256) {
        const int c = lcnt[b];
        if (c) lbase[b] = b * CAP + atomicAdd(&bin_cursor[b], c);
    }
    __syncthreads();
    #pragma unroll
    for (int j = 0; j < SC_EPT; j++) {
        if (bin[j] >= 0) edata[lbase[bin[j]] + lpos[j]] = pay[j];
    }
}

// ---------------------------------------------------------------------------
// Binsort body, SINGLE atomic pass (R11-verified pattern): the count pass's
// returning atomicAdd IS each edge's within-row rank (unrolled lp[18]
// register array); the scatter pass needs no atomics. Halves the per-CU
// LDS-atomic pipe time (R5/R6: ~4 cyc/lane, occupancy-independent).
// cnt from counts-cursor. Emits {beg,end} int2 per row.
// ---------------------------------------------------------------------------
static __device__ __forceinline__ void sort_body(char* smem, int b,
                                                 u32x2* __restrict__ edata,
                                                 const int* __restrict__ bin_cursor,
                                                 int2* __restrict__ rbe) {
    u32x2* ebuf = (u32x2*)smem;                    // CAP * 8 = 36,864 B
    int* rcnt = (int*)(smem + CAP * 8);            // 512 B
    int* rbase = rcnt + BIN_ROWS;                  // 512 B
    const int t = threadIdx.x;
    const int beg = b * CAP;
    const int cnt = min(bin_cursor[b], CAP);

    for (int e = t; e < cnt; e += 256)
        ebuf[e] = __builtin_nontemporal_load(edata + beg + e);
    if (t < BIN_ROWS) rcnt[t] = 0;
    __syncthreads();

    int lp[EPT_BS];
    #pragma unroll
    for (int k = 0; k < EPT_BS; k++) {
        const int e = t + k * 256;
        if (e < cnt) lp[k] = atomicAdd(&rcnt[ebuf[e].x >> 18], 1);
    }
    __syncthreads();

    const int v = (t < BIN_ROWS) ? rcnt[t] : 0;
    if (t < BIN_ROWS) rbase[t] = v;
    __syncthreads();
    #pragma unroll
    for (int off = 1; off < BIN_ROWS; off <<= 1) {
        const int u = (t < BIN_ROWS && t >= off) ? rbase[t - off] : 0;
        __syncthreads();
        if (t < BIN_ROWS) rbase[t] += u;
        __syncthreads();
    }
    if (t < BIN_ROWS) {
        const int ex = rbase[t] - v;
        rbase[t] = ex;                      // exclusive base
        const int row = b * BIN_ROWS + t;
        if (row < N_NODES) {
            int2 be;
            be.x = beg + ex;
            be.y = beg + ex + v;
            rbe[row] = be;
        }
    }
    __syncthreads();
    #pragma unroll
    for (int k = 0; k < EPT_BS; k++) {
        const int e = t + k * 256;
        if (e < cnt) {
            const u32x2 d = ebuf[e];
            const int pos = beg + rbase[d.x >> 18] + lp[k];
            u32x2 o;
            o.x = d.x & 0x3FFFFu;
            o.y = d.y;
            edata[pos] = o;
        }
    }
}

// ---------------------------------------------------------------------------
// Launch 1: blocks 0..1 = wconv (w -> wT packed bf16); blocks 2.. =
// binscatter at full occupancy (6.25 KB LDS). BYTE-IDENTICAL to R15.
// ---------------------------------------------------------------------------
__global__ __launch_bounds__(256) void scatwconv_kernel(const float* __restrict__ w,
                                                        u32* __restrict__ wTb,
                                                        const int* __restrict__ rows,
                                                        const int* __restrict__ cols,
                                                        const float* __restrict__ vals,
                                                        int* __restrict__ bin_cursor,
                                                        u32x2* __restrict__ edata) {
    __shared__ alignas(16) char smem[SCAT_SMEM];
    const int bid = blockIdx.x;
    if (bid < N_SUP) {
        const int s = bid;
        const int n = threadIdx.x >> 1;
        const int kh = (threadIdx.x & 1) * 64;
        const float* wp = w + (size_t)s * DIN * DOUT + n;
        u32 o[32];
        #pragma unroll
        for (int j = 0; j < 32; j++) {
            const float lo = wp[(size_t)(kh + 2 * j) * DOUT];
            const float hi = wp[(size_t)(kh + 2 * j + 1) * DOUT];
            o[j] = pack_bf16x2(lo, hi);
        }
        u32* op = wTb + ((size_t)s * 128 + n) * 64 + kh / 2;
        #pragma unroll
        for (int j = 0; j < 8; j++)
            *(u32x4*)(op + j * 4) = *(u32x4*)&o[j * 4];
        return;
    }
    scatter_body(smem, bid - N_SUP, rows, cols, vals, bin_cursor, edata);
}

// ---------------------------------------------------------------------------
// Launch 2: even blocks = GEMM (both supports, one x-stage), odd = binsort
// (single atomic pass). 1,564 blocks.
// ---------------------------------------------------------------------------
__global__ __launch_bounds__(256) void gemmsort_kernel(const float* __restrict__ x,
                                                       const u32* __restrict__ wTb,
                                                       u32* __restrict__ pre,
                                                       u32x2* __restrict__ edata,
                                                       const int* __restrict__ bin_cursor,
                                                       int2* __restrict__ rbe) {
    __shared__ alignas(16) char smem[GEMM_SMEM];
    const int bid = blockIdx.x;
    if (bid & 1) sort_body(smem, bid >> 1, edata, bin_cursor, rbe);
    else         gemm_body(smem, bid >> 1, x, wTb, pre);
}

// ---------------------------------------------------------------------------
// Gather-accumulate: BYTE-IDENTICAL to R9/R15 (verified ~130 us, at the
// ~10.4 B/cyc/CU narrow-coalesced random-access roofline).
// ---------------------------------------------------------------------------
__global__ __launch_bounds__(256, 6) void gather_kernel(const u32* __restrict__ pre,
                                                        const u32x2* __restrict__ edata,
                                                        const int2* __restrict__ rbe,
                                                        const float* __restrict__ bias,
                                                        float* __restrict__ out) {
    const int lane = threadIdx.x & 63;
    const int wid = threadIdx.x >> 6;
    const int row = blockIdx.x * 4 + wid;
    if (row >= N_NODES) return;

    const int2 be = rbe[row];
    int e = be.x;
    const int end = be.y;

    float ax = 0.f, ay = 0.f;

    if (e + 8 <= end) {
        u32x2 d[8];
        #pragma unroll
        for (int j = 0; j < 8; j++)
            d[j] = __builtin_nontemporal_load(edata + e + j);
        for (;;) {
            u32 u[8];
            #pragma unroll
            for (int j = 0; j < 8; j++)
                u[j] = pre[(u32)((d[j].x << 6) + (u32)lane)];
            const int en = e + 8;
            const bool more = (en + 8 <= end);   // wave-uniform
            u32x2 dn[8];
            if (more) {
                #pragma unroll
                for (int j = 0; j < 8; j++)
                    dn[j] = __builtin_nontemporal_load(edata + en + j);
            }
            #pragma unroll
            for (int j = 0; j < 8; j++) {
                const float v = __uint_as_float(d[j].y);
                ax = fmaf(v, __uint_as_float(u[j] << 16), ax);
                ay = fmaf(v, __uint_as_float(u[j] & 0xFFFF0000u), ay);
            }
            e = en;
            if (!more) break;
            #pragma unroll
            for (int j = 0; j < 8; j++) d[j] = dn[j];
        }
    }
    // mid: 4 edges per batch
    for (; e + 4 <= end; e += 4) {
        u32x2 d[4];
        #pragma unroll
        for (int j = 0; j < 4; j++)
            d[j] = __builtin_nontemporal_load(edata + e + j);
        u32 u[4];
        #pragma unroll
        for (int j = 0; j < 4; j++)
            u[j] = pre[(u32)((d[j].x << 6) + (u32)lane)];
        #pragma unroll
        for (int j = 0; j < 4; j++) {
            const float v = __uint_as_float(d[j].y);
            ax = fmaf(v, __uint_as_float(u[j] << 16), ax);
            ay = fmaf(v, __uint_as_float(u[j] & 0xFFFF0000u), ay);
        }
    }
    // tail
    for (; e < end; e++) {
        const u32x2 d = __builtin_nontemporal_load(edata + e);
        const u32 u = pre[(u32)((d.x << 6) + (u32)lane)];
        const float v = __uint_as_float(d.y);
        ax = fmaf(v, __uint_as_float(u << 16), ax);
        ay = fmaf(v, __uint_as_float(u & 0xFFFF0000u), ay);
    }

    const float2 b = *(const float2*)(bias + lane * 2);
    f32x2 r;
    r.x = fmaxf(ax + b.x, 0.f);
    r.y = fmaxf(ay + b.y, 0.f);
    __builtin_nontemporal_store(r, (f32x2*)(out + (size_t)row * DOUT + lane * 2));
}

extern "C" void kernel_launch(void* const* d_in, const int* in_sizes, int n_in,
                              void* d_out, int out_size, void* d_ws, size_t ws_size,
                              hipStream_t stream) {
    (void)in_sizes; (void)n_in; (void)out_size; (void)ws_size;
    const float* x        = (const float*)d_in[0];   // [N, 128]
    const float* w        = (const float*)d_in[1];   // [2, 128, 128]
    const float* bias     = (const float*)d_in[2];   // [128]
    const float* sup_vals = (const float*)d_in[3];   // [2, E] flat
    const int*   sup_rows = (const int*)d_in[4];     // [2, E] flat
    const int*   sup_cols = (const int*)d_in[5];     // [2, E] flat
    float* out = (float*)d_out;                      // [N, 128]

    // ws layout: pre | edata (padded bins) | rbe | bin_cursor | wTb (~81 MB)
    char* ws = (char*)d_ws;
    u32*   pre       = (u32*)ws;                                        // 51.2 MB
    u32x2* edata     = (u32x2*)(ws + (size_t)N_SUP * N_NODES * 64 * 4); // 28.8 MB
    int2*  rbe       = (int2*)((char*)edata + (size_t)NBINS * CAP * 8); // 800 KB
    int*   bin_cursor= (int*)(rbe + N_NODES);                           // NBINS
    u32*   wTb       = (u32*)(bin_cursor + NBINS + 2);                  // 64 KB

    // 1. zero per-bin counts (scatter adds b*CAP itself)
    (void)hipMemsetAsync(bin_cursor, 0, NBINS * sizeof(int), stream);
    // 2. wconv (2 blocks) + binscatter at full occupancy
    scatwconv_kernel<<<N_SUP + NBLK_SC, 256, 0, stream>>>(w, wTb, sup_rows, sup_cols,
                                                          sup_vals, bin_cursor, edata);
    // 3. GEMM (both supports per block, single x-stage) + binsort
    //    (single-atomic-pass) in one launch
    gemmsort_kernel<<<2 * NBLK_GEMM, 256, 0, stream>>>(x, wTb, pre, edata,
                                                       bin_cursor, rbe);
    // 4. row gather + bias + ReLU (no atomics)
    gather_kernel<<<(N_NODES + 3) / 4, 256, 0, stream>>>(pre, edata, rbe, bias, out);
}